// Round 15
// baseline (9906.865 us; speedup 1.0000x reference)
//
#include <hip/hip_runtime.h>
#include <cmath>

#define TT 512
#define BB 64
#define HH 512
#define II 128
#define NBLK 256

typedef float v2f __attribute__((ext_vector_type(2)));
__device__ __forceinline__ v2f fma2(v2f a, v2f b, v2f c) { return __builtin_elementwise_fma(a, b, c); }

// dynamic LDS floats: part 16*16*64 =16384 | gates 16*64 =1024 | cst 256 |
// bsum 16  => ~70 KB (weights NO LONGER in LDS — they stream on the SMEM pipe)
#define SMEM_FLOATS (16384 + 1024 + 256 + 16)
#define SMEM_BYTES  (SMEM_FLOATS * 4)

__device__ __forceinline__ float sigm(float v) { return 1.0f / (1.0f + expf(-v)); }
__device__ __forceinline__ unsigned umin2(unsigned a, unsigned b) { return a < b ? a : b; }
#define CBAR() asm volatile("" ::: "memory")   // compiler-only reorder fence

// One k-slice: 16 weights (rows 0..15) from GLOBAL wT (wave-uniform address ->
// scalar s_load path; SGPR operand feeds v_pk_fma directly). 8 v_pk_fma per k.
__device__ __forceinline__ void step(const float* wk, float v, v2f (&acc)[8]) {
  const float4* wp = (const float4*)wk;
  const float4 w0 = wp[0], w1 = wp[1], w2 = wp[2], w3 = wp[3];
  const v2f vb = (v2f){v, v};
  acc[0] = fma2((v2f){w0.x, w0.y}, vb, acc[0]);
  acc[1] = fma2((v2f){w0.z, w0.w}, vb, acc[1]);
  acc[2] = fma2((v2f){w1.x, w1.y}, vb, acc[2]);
  acc[3] = fma2((v2f){w1.z, w1.w}, vb, acc[3]);
  acc[4] = fma2((v2f){w2.x, w2.y}, vb, acc[4]);
  acc[5] = fma2((v2f){w2.z, w2.w}, vb, acc[5]);
  acc[6] = fma2((v2f){w3.x, w3.y}, vb, acc[6]);
  acc[7] = fma2((v2f){w3.z, w3.w}, vb, acc[7]);
}

// Bypass (relaxed AGENT atomic) batch loads: served from the coherence point,
// immune to stale local lines; compiler-managed waits.
template<int KN>
__device__ __forceinline__ void loadva(const float* __restrict__ src, int k0,
                                       int b, float (&v)[KN]) {
#pragma unroll
  for (int i = 0; i < KN; ++i)
    v[i] = __hip_atomic_load(src + (size_t)(k0 + i) * BB + b,
                             __ATOMIC_RELAXED, __HIP_MEMORY_SCOPE_AGENT);
}
// Plain cached batch load (x only — immutable, L2-resident).
template<int KN>
__device__ __forceinline__ void loadv(const float* __restrict__ src, int k0,
                                      int b, float (&v)[KN]) {
#pragma unroll
  for (int i = 0; i < KN; ++i) v[i] = src[(size_t)(k0 + i) * BB + b];
}
template<int KN>
__device__ __forceinline__ void consume(const float* __restrict__ wbase, int k0,
                                        const float (&v)[KN], v2f (&acc)[8]) {
#pragma unroll
  for (int i = 0; i < KN; ++i) step(wbase + (size_t)(k0 + i) * 16, v[i], acc);
}

// 32-k span, 8-deep ping-pong (<=16 staging floats live -> no spills).
__device__ __forceinline__ void span32(const float* __restrict__ src,
                                       const float* __restrict__ wbase,
                                       int k0, int b, v2f (&acc)[8]) {
  float va[8], vb_[8];
  loadva<8>(src, k0, b, va);
  loadva<8>(src, k0 + 8, b, vb_);
  consume<8>(wbase, k0, va, acc);
  loadva<8>(src, k0 + 16, b, va);
  consume<8>(wbase, k0 + 8, vb_, acc);
  loadva<8>(src, k0 + 24, b, vb_);
  consume<8>(wbase, k0 + 16, va, acc);
  consume<8>(wbase, k0 + 24, vb_, acc);
}

// ---------------------------------------------------------------------------
// Transpose x: [64][512][128] (b,t,k) -> xT: [512][128][64] (t,k,b)
// ---------------------------------------------------------------------------
__global__ __launch_bounds__(1024) void k_transpose_x(const float* __restrict__ x,
                                                      float* __restrict__ xT) {
  __shared__ float tile[64][65];
  const int t  = blockIdx.x >> 1;
  const int k0 = (blockIdx.x & 1) << 6;
  const int lk = threadIdx.x & 63;
  const int lb = threadIdx.x >> 6;
#pragma unroll
  for (int bp = 0; bp < 64; bp += 16) {
    const int b = bp + lb;
    tile[lk][b] = x[((size_t)b * TT + t) * II + k0 + lk];
  }
  __syncthreads();
  const int b2  = threadIdx.x & 63;
  const int kk0 = threadIdx.x >> 6;
#pragma unroll
  for (int kp = 0; kp < 64; kp += 16) {
    const int kk = kp + kk0;
    xT[((size_t)t * II + k0 + kk) * BB + b2] = tile[kk][b2];
  }
}

// ---------------------------------------------------------------------------
// Prologue: per-block k-major weight image. wT[bid][k][lr] (16 floats/k).
// One-time ~13 MB read / 16 MB write.
// ---------------------------------------------------------------------------
__global__ __launch_bounds__(1024) void k_prep_w(
    const float* __restrict__ W_ih0, const float* __restrict__ W_hh0,
    const float* __restrict__ W_ih1, const float* __restrict__ W_hh1,
    float* __restrict__ wT) {
  const int bid = blockIdx.x;
  const int L   = bid >> 7;
  const int ub  = (bid & 127) << 2;
  const float* WA = L ? W_ih1 : W_ih0;
  const float* WB = L ? W_hh1 : W_hh0;
  const int KA = L ? HH : II;
  const int ktot = KA + HH;
  float* dst = wT + (size_t)bid * (16 * 1024);
  for (int idx = threadIdx.x; idx < 16 * ktot; idx += 1024) {
    const int k  = idx >> 4;
    const int lr = idx & 15;
    const int u = lr >> 2, q = lr & 3;
    const int G = q * HH + ub + u;           // i,f,g,o chunk order
    dst[idx] = (k < KA) ? WA[G * KA + k] : WB[G * HH + (k - KA)];
  }
}

__global__ void k_init_flags(unsigned* flags) { flags[threadIdx.x] = 0u; }

// ---------------------------------------------------------------------------
// Persistent pipelined 2-layer LSTM — round-13's proven zero-fence protocol
// (swap-with-return publish, bypass atomic consumer loads, full flag barrier).
// DELTA vs round 13: weights moved OFF the LDS pipe. They stream from global
// wT (k-major, L2-resident: 64KB/block, 2MB/XCD) through the SCALAR path —
// the address is wave-uniform (kseg==wave id, forced visible to the compiler
// via readfirstlane) so loads lower to s_load_dwordx4/x16 on the idle SMEM
// pipe and feed v_pk_fma as SGPR operands. Round 14's accounting showed the
// old uniform ds_read_b128 storm (4096/block/phase, ~8-12cy each on the one
// LDS pipe) WAS the ~15us phase. LDS now holds only the 70KB reduce buffers.
// ---------------------------------------------------------------------------
__global__ __launch_bounds__(1024, 4) void k_lstm_persist(
    const float* __restrict__ xT, const float* __restrict__ wT,
    const float* __restrict__ b_ih0, const float* __restrict__ b_hh0,
    const float* __restrict__ b_ih1, const float* __restrict__ b_hh1,
    float* __restrict__ h0ring, float* __restrict__ h1ring,
    unsigned* __restrict__ flags)
{
  extern __shared__ float smem[];
  float* part  = smem;            // [row16][kseg16][b64]
  float* gates = part + 16384;    // [row16][b64]
  float* cst   = gates + 1024;    // [u4][b64]
  float* bsum  = cst + 256;       // [16]

  const int bid = blockIdx.x;
  const int L   = bid >> 7;
  const int ub  = (bid & 127) << 2;   // 4 hidden units per block
  const int tid = threadIdx.x;
  const int KA  = L ? HH : II;

  // per-block weight image (uniform base)
  const float* wblk = wT + (size_t)bid * (16 * 1024);

  if (tid < 16) {
    const int u = tid >> 2, q = tid & 3;
    const int G = q * HH + ub + u;
    bsum[tid] = L ? (b_ih1[G] + b_hh1[G]) : (b_ih0[G] + b_hh0[G]);
  }
  if (tid < 256) cst[tid] = 0.0f;
  __syncthreads();

  // kseg is physically wave-uniform (tid>>6 == wave id); readfirstlane makes
  // the compiler PROVE it, so weight addresses become scalar (SMEM path).
  const int kseg = __builtin_amdgcn_readfirstlane(tid >> 6);   // 0..15
  const int b    = tid & 63;

  for (int s = 0; s <= TT; ++s) {
    const int t = L ? (s - 1) : s;
    const bool active = (t >= 0 && t < TT);
    const bool first  = (t == 0);

    v2f acc[8];
#pragma unroll
    for (int j = 0; j < 8; ++j) acc[j] = (v2f){0.0f, 0.0f};

    // ---- L0 x loads BEFORE the wait (immutable; complete during spin) ----
    float xv[8];
    if (active && L == 0) {
      loadv<8>(xT + (size_t)t * (II * BB), kseg * 8, b, xv);
    }

    // ---- wait: all blocks published phase s-1 (no fence needed) ----
    if (s > 0) {
      if (tid < 64) {
        const unsigned tgt = (unsigned)s;
        for (;;) {
          const unsigned m0 = __hip_atomic_load(flags + tid,       __ATOMIC_RELAXED, __HIP_MEMORY_SCOPE_AGENT);
          const unsigned m1 = __hip_atomic_load(flags + tid +  64, __ATOMIC_RELAXED, __HIP_MEMORY_SCOPE_AGENT);
          const unsigned m2 = __hip_atomic_load(flags + tid + 128, __ATOMIC_RELAXED, __HIP_MEMORY_SCOPE_AGENT);
          const unsigned m3 = __hip_atomic_load(flags + tid + 192, __ATOMIC_RELAXED, __HIP_MEMORY_SCOPE_AGENT);
          const unsigned mn = umin2(umin2(m0, m1), umin2(m2, m3));
          if (__all(mn >= tgt)) break;
          __builtin_amdgcn_s_sleep(1);
        }
      }
      __syncthreads();
      CBAR();   // keep h loads below the spin at IR level
    }

    if (active) {
      if (L == 0) {
        consume<8>(wblk, kseg * 8, xv, acc);
        if (!first) {  // B-part: h0[s-1] @ parity (s-1)&1; weights at k=II+
          span32(h0ring + (size_t)((s - 1) & 1) * (HH * BB),
                 wblk + (size_t)II * 16, kseg * 32, b, acc);
        }
      } else {
        const float* h0p = h0ring + (size_t)((s - 1) & 1) * (HH * BB);
        span32(h0p, wblk, kseg * 32, b, acc);
        if (!first) {  // B-part: h1[s-2] @ parity s&1; weights at k=HH+
          span32(h1ring + (size_t)(s & 1) * (HH * BB),
                 wblk + (size_t)HH * 16, kseg * 32, b, acc);
        }
      }

      // ---- reduce 16 ksegs -> gates (lanes = b: conflict-free) ----
#pragma unroll
      for (int j = 0; j < 4; ++j) {
        part[(((j << 2) + 0) * 16 + kseg) * 64 + b] = acc[(j << 1)].x;
        part[(((j << 2) + 1) * 16 + kseg) * 64 + b] = acc[(j << 1)].y;
        part[(((j << 2) + 2) * 16 + kseg) * 64 + b] = acc[(j << 1) + 1].x;
        part[(((j << 2) + 3) * 16 + kseg) * 64 + b] = acc[(j << 1) + 1].y;
      }
      __syncthreads();
      {
        const int row = tid >> 6;
        const int bb  = tid & 63;
        float g = 0.0f;
#pragma unroll
        for (int ks = 0; ks < 16; ++ks) g += part[(row * 16 + ks) * 64 + bb];
        gates[row * 64 + bb] = g + bsum[row];
      }
      __syncthreads();

      if (tid < 256) {  // cell update; h published via swap-with-return
        const int u = tid >> 6, bb = tid & 63;
        const float gi = sigm(gates[((u << 2) + 0) * 64 + bb]);
        const float gf = sigm(gates[((u << 2) + 1) * 64 + bb]);
        const float gg = tanhf(gates[((u << 2) + 2) * 64 + bb]);
        const float go = sigm(gates[((u << 2) + 3) * 64 + bb]);
        const float cold = first ? 0.0f : cst[u * 64 + bb];
        const float cn = gf * cold + gi * gg;
        const float hn = go * tanhf(cn);
        cst[u * 64 + bb] = cn;
        float* hdst = (L ? h1ring : h0ring) + (size_t)(t & 1) * (HH * BB);
        // swap-with-return: the returned value proves the op performed at the
        // MALL; the asm sink forces the s_waitcnt on it before the barrier.
        float old = __hip_atomic_exchange(hdst + (ub + u) * 64 + bb, hn,
                                          __ATOMIC_RELAXED, __HIP_MEMORY_SCOPE_AGENT);
        asm volatile("" :: "v"(old));
      }
    }

    // all swaps' returns received (h at MALL) before any thread passes here;
    // the flag store is issued strictly afterwards -> cannot be seen early.
    __syncthreads();
    if (tid == 0) {
      __hip_atomic_store(flags + bid, (unsigned)(s + 1),
                         __ATOMIC_RELAXED, __HIP_MEMORY_SCOPE_AGENT);
    }
  }
}

// ---------------------------------------------------------------------------
// out[b] = sum_j h1_last[j][b] * Wl[j] + bl[0]
// ---------------------------------------------------------------------------
__global__ __launch_bounds__(512) void k_final(const float* __restrict__ h1last,
                                               const float* __restrict__ Wl,
                                               const float* __restrict__ bl,
                                               float* __restrict__ out) {
  __shared__ float red[8][64];
  const int jg = threadIdx.x >> 6, b = threadIdx.x & 63;
  float a = 0.0f;
  for (int jj = 0; jj < 64; ++jj) {
    const int j = (jg << 6) + jj;
    a += h1last[j * BB + b] * Wl[j];
  }
  red[jg][b] = a;
  __syncthreads();
  if (threadIdx.x < 64) {
    float s = bl[0];
#pragma unroll
    for (int g = 0; g < 8; ++g) s += red[g][threadIdx.x];
    out[threadIdx.x] = s;
  }
}

extern "C" void kernel_launch(void* const* d_in, const int* in_sizes, int n_in,
                              void* d_out, int out_size, void* d_ws, size_t ws_size,
                              hipStream_t stream) {
  (void)in_sizes; (void)n_in; (void)out_size; (void)ws_size;
  const float* x     = (const float*)d_in[0];
  const float* W_ih0 = (const float*)d_in[1];
  const float* W_hh0 = (const float*)d_in[2];
  const float* b_ih0 = (const float*)d_in[3];
  const float* b_hh0 = (const float*)d_in[4];
  const float* W_ih1 = (const float*)d_in[5];
  const float* W_hh1 = (const float*)d_in[6];
  const float* b_ih1 = (const float*)d_in[7];
  const float* b_hh1 = (const float*)d_in[8];
  const float* Wl    = (const float*)d_in[9];
  const float* bl    = (const float*)d_in[10];
  float* out = (float*)d_out;

  float* ws       = (float*)d_ws;
  float* xT       = ws;                           // 512*128*64   = 16 MB
  float* wT       = xT + (size_t)TT * II * BB;    // 256*16*1024  = 16 MB
  float* h0ring   = wT + (size_t)NBLK * 16 * 1024;  // 2*512*64
  float* h1ring   = h0ring + 2 * HH * BB;           // 2*512*64
  unsigned* flags = (unsigned*)(h1ring + 2 * HH * BB);  // 256 u32

  k_transpose_x<<<1024, 1024, 0, stream>>>(x, xT);
  k_prep_w<<<NBLK, 1024, 0, stream>>>(W_ih0, W_hh0, W_ih1, W_hh1, wT);
  k_init_flags<<<1, NBLK, 0, stream>>>(flags);

  hipFuncSetAttribute((const void*)k_lstm_persist,
                      hipFuncAttributeMaxDynamicSharedMemorySize, SMEM_BYTES);

  void* args[] = {
    (void*)&xT, (void*)&wT,
    (void*)&b_ih0, (void*)&b_hh0, (void*)&b_ih1, (void*)&b_hh1,
    (void*)&h0ring, (void*)&h1ring, (void*)&flags,
  };
  // Cooperative launch kept ONLY for the co-residency guarantee; sync is ours.
  hipLaunchCooperativeKernel((void*)k_lstm_persist, dim3(NBLK), dim3(1024),
                             args, SMEM_BYTES, stream);

  // h1[T-1] lives at ring parity (T-1)&1 == 1
  k_final<<<1, 512, 0, stream>>>(h1ring + HH * BB, Wl, bl, out);
}

// Round 16
// 7860.294 us; speedup vs baseline: 1.2604x; 1.2604x over previous
//
#include <hip/hip_runtime.h>
#include <cmath>

#define TT 512
#define BB 64
#define HH 512
#define II 128
#define NBLK 256

typedef float v2f __attribute__((ext_vector_type(2)));
__device__ __forceinline__ v2f fma2(v2f a, v2f b, v2f c) { return __builtin_elementwise_fma(a, b, c); }

// dynamic LDS floats: wlds 16*1024 =16384 | part 16*16*64 =16384 |
// gates 16*64 =1024 | cst 256 | bsum 16   => ~133 KB  (=> 1 block/CU)
#define SMEM_FLOATS (16384 + 16384 + 1024 + 256 + 16)
#define SMEM_BYTES  (SMEM_FLOATS * 4)

__device__ __forceinline__ float sigm(float v) { return 1.0f / (1.0f + expf(-v)); }
__device__ __forceinline__ unsigned umin2(unsigned a, unsigned b) { return a < b ? a : b; }
#define CBAR() asm volatile("" ::: "memory")   // compiler-only reorder fence

// One k-slice: 16 weights (rows 0..15) from LDS (wave-uniform broadcast),
// 8 v_pk_fma_f32. acc[j] covers rows (2j, 2j+1).
__device__ __forceinline__ void step(const float* wk, float v, v2f (&acc)[8]) {
  const float4* wp = (const float4*)wk;
  const float4 w0 = wp[0], w1 = wp[1], w2 = wp[2], w3 = wp[3];
  const v2f vb = (v2f){v, v};
  acc[0] = fma2((v2f){w0.x, w0.y}, vb, acc[0]);
  acc[1] = fma2((v2f){w0.z, w0.w}, vb, acc[1]);
  acc[2] = fma2((v2f){w1.x, w1.y}, vb, acc[2]);
  acc[3] = fma2((v2f){w1.z, w1.w}, vb, acc[3]);
  acc[4] = fma2((v2f){w2.x, w2.y}, vb, acc[4]);
  acc[5] = fma2((v2f){w2.z, w2.w}, vb, acc[5]);
  acc[6] = fma2((v2f){w3.x, w3.y}, vb, acc[6]);
  acc[7] = fma2((v2f){w3.z, w3.w}, vb, acc[7]);
}

// h loads. DEEP (never-reused ring): plain CACHED loads — first touch per
// line in this call is the producer's MALL write-through, so no stale local
// hit is possible; fills are L2-shared across the XCD's 32 blocks.
// Non-deep fallback: round-13's proven bypass atomic loads (read AT MALL).
template<bool DEEP, int KN>
__device__ __forceinline__ void loadh(const float* __restrict__ src, int k0,
                                      int b, float (&v)[KN]) {
#pragma unroll
  for (int i = 0; i < KN; ++i) {
    if constexpr (DEEP)
      v[i] = src[(size_t)(k0 + i) * BB + b];
    else
      v[i] = __hip_atomic_load(src + (size_t)(k0 + i) * BB + b,
                               __ATOMIC_RELAXED, __HIP_MEMORY_SCOPE_AGENT);
  }
}
// Plain cached batch load (x only — immutable, L2-resident).
template<int KN>
__device__ __forceinline__ void loadv(const float* __restrict__ src, int k0,
                                      int b, float (&v)[KN]) {
#pragma unroll
  for (int i = 0; i < KN; ++i) v[i] = src[(size_t)(k0 + i) * BB + b];
}
template<int KN>
__device__ __forceinline__ void consume(const float* __restrict__ wbase, int k0,
                                        const float (&v)[KN], v2f (&acc)[8]) {
#pragma unroll
  for (int i = 0; i < KN; ++i) step(wbase + (size_t)(k0 + i) * 16, v[i], acc);
}

// 32-k span, 8-deep ping-pong (<=16 staging floats live -> no spills).
template<bool DEEP>
__device__ __forceinline__ void span32(const float* __restrict__ src,
                                       const float* __restrict__ wbase,
                                       int k0, int b, v2f (&acc)[8]) {
  float va[8], vb_[8];
  loadh<DEEP, 8>(src, k0, b, va);
  loadh<DEEP, 8>(src, k0 + 8, b, vb_);
  consume<8>(wbase, k0, va, acc);
  loadh<DEEP, 8>(src, k0 + 16, b, va);
  consume<8>(wbase, k0 + 8, vb_, acc);
  loadh<DEEP, 8>(src, k0 + 24, b, vb_);
  consume<8>(wbase, k0 + 16, va, acc);
  consume<8>(wbase, k0 + 24, vb_, acc);
}

// ---------------------------------------------------------------------------
// Transpose x: [64][512][128] (b,t,k) -> xT: [512][128][64] (t,k,b)
// ---------------------------------------------------------------------------
__global__ __launch_bounds__(1024) void k_transpose_x(const float* __restrict__ x,
                                                      float* __restrict__ xT) {
  __shared__ float tile[64][65];
  const int t  = blockIdx.x >> 1;
  const int k0 = (blockIdx.x & 1) << 6;
  const int lk = threadIdx.x & 63;
  const int lb = threadIdx.x >> 6;
#pragma unroll
  for (int bp = 0; bp < 64; bp += 16) {
    const int b = bp + lb;
    tile[lk][b] = x[((size_t)b * TT + t) * II + k0 + lk];
  }
  __syncthreads();
  const int b2  = threadIdx.x & 63;
  const int kk0 = threadIdx.x >> 6;
#pragma unroll
  for (int kp = 0; kp < 64; kp += 16) {
    const int kk = kp + kk0;
    xT[((size_t)t * II + k0 + kk) * BB + b2] = tile[kk][b2];
  }
}

__global__ void k_init_flags(unsigned* flags) { flags[threadIdx.x] = 0u; }

// ---------------------------------------------------------------------------
// Persistent pipelined 2-layer LSTM — round-13's proven zero-fence protocol.
// DEEP=true: h rings have ONE SLOT PER TIMESTEP (slot = t; never reused in a
//   call) -> consumers use plain CACHED loads (L2-shared per XCD, ~3x lower
//   latency, 32x less MALL read traffic). Stale lines from the previous graph
//   replay are dropped by ONE acquire fence (buffer_inv) at kernel entry.
// DEEP=false: round-13 exact fallback (depth-2 parity ring, bypass loads).
// Producer: h published via 64-bit atomic EXCHANGE (x2 packed: halves the
//   per-cache-line serialization at the MALL); returns force s_waitcnt before
//   the barrier; flag store issues strictly after -> ordering by construction.
// ---------------------------------------------------------------------------
template<bool DEEP>
__global__ __launch_bounds__(1024, 4) void k_lstm_persist(
    const float* __restrict__ xT,
    const float* __restrict__ W_ih0, const float* __restrict__ W_hh0,
    const float* __restrict__ b_ih0, const float* __restrict__ b_hh0,
    const float* __restrict__ W_ih1, const float* __restrict__ W_hh1,
    const float* __restrict__ b_ih1, const float* __restrict__ b_hh1,
    float* __restrict__ h0ring, float* __restrict__ h1ring,
    unsigned* __restrict__ flags)
{
  extern __shared__ float smem[];
  float* wlds  = smem;            // [k up to 1024][16 rows] k-major
  float* part  = wlds + 16384;    // [row16][kseg16][b64]
  float* gates = part + 16384;    // [row16][b64]
  float* cst   = gates + 1024;    // [u4][b64]
  float* bsum  = cst + 256;       // [16]

  // Drop any stale L1/L2 lines left by the PREVIOUS graph replay (the deep
  // ring's within-call safety is by construction; this closes the replay
  // hole). Once per call — negligible.
  __builtin_amdgcn_fence(__ATOMIC_ACQUIRE, "agent");

  const int bid = blockIdx.x;
  const int L   = bid >> 7;
  const int ub  = (bid & 127) << 2;   // 4 hidden units per block
  const int tid = threadIdx.x;

  const float* WA = L ? W_ih1 : W_ih0;
  const float* WB = L ? W_hh1 : W_hh0;
  const int KA = L ? HH : II;

  // ---- one-time: stage weights k-major + bias sums + c=0 ----
  const int ktot = KA + HH;
  for (int idx = tid; idx < 16 * ktot; idx += 1024) {
    const int k  = idx >> 4;
    const int lr = idx & 15;
    const int u = lr >> 2, q = lr & 3;
    const int G = q * HH + ub + u;           // i,f,g,o chunk order
    wlds[idx] = (k < KA) ? WA[G * KA + k] : WB[G * HH + (k - KA)];
  }
  if (tid < 16) {
    const int u = tid >> 2, q = tid & 3;
    const int G = q * HH + ub + u;
    bsum[tid] = L ? (b_ih1[G] + b_hh1[G]) : (b_ih0[G] + b_hh0[G]);
  }
  if (tid < 256) cst[tid] = 0.0f;
  __syncthreads();

  const int kseg = tid >> 6;   // 0..15
  const int b    = tid & 63;

  for (int s = 0; s <= TT; ++s) {
    const int t = L ? (s - 1) : s;
    const bool active = (t >= 0 && t < TT);
    const bool first  = (t == 0);

    // ring slots: DEEP -> slot = timestep (never reused); else parity
    const size_t sl_h0rd = DEEP ? (size_t)(s - 1) : (size_t)((s - 1) & 1);
    const size_t sl_h1rd = DEEP ? (size_t)(s - 2) : (size_t)(s & 1);
    const size_t sl_wr   = DEEP ? (size_t)t       : (size_t)(t & 1);

    v2f acc[8];
#pragma unroll
    for (int j = 0; j < 8; ++j) acc[j] = (v2f){0.0f, 0.0f};

    // ---- L0 x loads BEFORE the wait (immutable; complete during spin) ----
    float xv[8];
    if (active && L == 0) {
      loadv<8>(xT + (size_t)t * (II * BB), kseg * 8, b, xv);
    }

    // ---- wait: all blocks published phase s-1 (no fence needed) ----
    if (s > 0) {
      if (tid < 64) {
        const unsigned tgt = (unsigned)s;
        for (;;) {
          const unsigned m0 = __hip_atomic_load(flags + tid,       __ATOMIC_RELAXED, __HIP_MEMORY_SCOPE_AGENT);
          const unsigned m1 = __hip_atomic_load(flags + tid +  64, __ATOMIC_RELAXED, __HIP_MEMORY_SCOPE_AGENT);
          const unsigned m2 = __hip_atomic_load(flags + tid + 128, __ATOMIC_RELAXED, __HIP_MEMORY_SCOPE_AGENT);
          const unsigned m3 = __hip_atomic_load(flags + tid + 192, __ATOMIC_RELAXED, __HIP_MEMORY_SCOPE_AGENT);
          const unsigned mn = umin2(umin2(m0, m1), umin2(m2, m3));
          if (__all(mn >= tgt)) break;
          __builtin_amdgcn_s_sleep(1);
        }
      }
      __syncthreads();
      CBAR();   // keep h loads below the spin at IR level
    }

    if (active) {
      if (L == 0) {
        if (!first) {
          // issue first h0 batches BEFORE consuming x: hides load latency
          const float* src = h0ring + sl_h0rd * (HH * BB);
          const float* wh  = wlds + (size_t)II * 16;
          const int k0 = kseg * 32;
          float va[8], vb_[8];
          loadh<DEEP, 8>(src, k0, b, va);
          loadh<DEEP, 8>(src, k0 + 8, b, vb_);
          consume<8>(wlds, kseg * 8, xv, acc);
          consume<8>(wh, k0, va, acc);
          loadh<DEEP, 8>(src, k0 + 16, b, va);
          consume<8>(wh, k0 + 8, vb_, acc);
          loadh<DEEP, 8>(src, k0 + 24, b, vb_);
          consume<8>(wh, k0 + 16, va, acc);
          consume<8>(wh, k0 + 24, vb_, acc);
        } else {
          consume<8>(wlds, kseg * 8, xv, acc);
        }
      } else {
        const float* h0p = h0ring + sl_h0rd * (HH * BB);
        span32<DEEP>(h0p, wlds, kseg * 32, b, acc);
        if (!first) {
          span32<DEEP>(h1ring + sl_h1rd * (HH * BB),
                       wlds + (size_t)HH * 16, kseg * 32, b, acc);
        }
      }

      // ---- reduce 16 ksegs -> gates (lanes = b: conflict-free) ----
#pragma unroll
      for (int j = 0; j < 4; ++j) {
        part[(((j << 2) + 0) * 16 + kseg) * 64 + b] = acc[(j << 1)].x;
        part[(((j << 2) + 1) * 16 + kseg) * 64 + b] = acc[(j << 1)].y;
        part[(((j << 2) + 2) * 16 + kseg) * 64 + b] = acc[(j << 1) + 1].x;
        part[(((j << 2) + 3) * 16 + kseg) * 64 + b] = acc[(j << 1) + 1].y;
      }
      __syncthreads();
      {
        const int row = tid >> 6;
        const int bb  = tid & 63;
        float g = 0.0f;
#pragma unroll
        for (int ks = 0; ks < 16; ++ks) g += part[(row * 16 + ks) * 64 + bb];
        gates[row * 64 + bb] = g + bsum[row];
      }
      __syncthreads();

      if (tid < 128) {  // cell update: 2 batch elems/thread, 64-bit swaps
        const int u   = tid >> 5;
        const int bb0 = (tid & 31) << 1, bb1 = bb0 + 1;
        const float gi0 = sigm(gates[((u << 2) + 0) * 64 + bb0]);
        const float gf0 = sigm(gates[((u << 2) + 1) * 64 + bb0]);
        const float gg0 = tanhf(gates[((u << 2) + 2) * 64 + bb0]);
        const float go0 = sigm(gates[((u << 2) + 3) * 64 + bb0]);
        const float gi1 = sigm(gates[((u << 2) + 0) * 64 + bb1]);
        const float gf1 = sigm(gates[((u << 2) + 1) * 64 + bb1]);
        const float gg1 = tanhf(gates[((u << 2) + 2) * 64 + bb1]);
        const float go1 = sigm(gates[((u << 2) + 3) * 64 + bb1]);
        const float c0 = first ? 0.0f : cst[u * 64 + bb0];
        const float c1 = first ? 0.0f : cst[u * 64 + bb1];
        const float cn0 = gf0 * c0 + gi0 * gg0;
        const float cn1 = gf1 * c1 + gi1 * gg1;
        const float hn0 = go0 * tanhf(cn0);
        const float hn1 = go1 * tanhf(cn1);
        cst[u * 64 + bb0] = cn0;
        cst[u * 64 + bb1] = cn1;
        float* hdst = (L ? h1ring : h0ring) + sl_wr * (HH * BB);
        unsigned long long pk =
            (unsigned long long)__float_as_uint(hn0) |
            ((unsigned long long)__float_as_uint(hn1) << 32);
        // 64-bit swap-with-return: performed AT the MALL; the asm sink forces
        // the s_waitcnt on the return before the barrier below.
        unsigned long long old = __hip_atomic_exchange(
            (unsigned long long*)(hdst + (ub + u) * 64 + bb0), pk,
            __ATOMIC_RELAXED, __HIP_MEMORY_SCOPE_AGENT);
        asm volatile("" :: "v"(old));
      }
    }

    // all swaps' returns received (h at MALL) before any thread passes here;
    // the flag store is issued strictly afterwards -> cannot be seen early.
    __syncthreads();
    if (tid == 0 && s < TT) {   // last phase: nobody consumes the flag
      __hip_atomic_store(flags + bid, (unsigned)(s + 1),
                         __ATOMIC_RELAXED, __HIP_MEMORY_SCOPE_AGENT);
    }
  }
}

// ---------------------------------------------------------------------------
// out[b] = sum_j h1_last[j][b] * Wl[j] + bl[0]
// ---------------------------------------------------------------------------
__global__ __launch_bounds__(512) void k_final(const float* __restrict__ h1last,
                                               const float* __restrict__ Wl,
                                               const float* __restrict__ bl,
                                               float* __restrict__ out) {
  __shared__ float red[8][64];
  const int jg = threadIdx.x >> 6, b = threadIdx.x & 63;
  float a = 0.0f;
  for (int jj = 0; jj < 64; ++jj) {
    const int j = (jg << 6) + jj;
    a += h1last[j * BB + b] * Wl[j];
  }
  red[jg][b] = a;
  __syncthreads();
  if (threadIdx.x < 64) {
    float s = bl[0];
#pragma unroll
    for (int g = 0; g < 8; ++g) s += red[g][threadIdx.x];
    out[threadIdx.x] = s;
  }
}

extern "C" void kernel_launch(void* const* d_in, const int* in_sizes, int n_in,
                              void* d_out, int out_size, void* d_ws, size_t ws_size,
                              hipStream_t stream) {
  (void)in_sizes; (void)n_in; (void)out_size;
  const float* x     = (const float*)d_in[0];
  const float* W_ih0 = (const float*)d_in[1];
  const float* W_hh0 = (const float*)d_in[2];
  const float* b_ih0 = (const float*)d_in[3];
  const float* b_hh0 = (const float*)d_in[4];
  const float* W_ih1 = (const float*)d_in[5];
  const float* W_hh1 = (const float*)d_in[6];
  const float* b_ih1 = (const float*)d_in[7];
  const float* b_hh1 = (const float*)d_in[8];
  const float* Wl    = (const float*)d_in[9];
  const float* bl    = (const float*)d_in[10];
  float* out = (float*)d_out;

  // Deep layout: xT 16MB + 2 rings x 513 slots x 128KB (~147.5MB total).
  const size_t xt_f   = (size_t)TT * II * BB;
  const size_t ring_f = (size_t)(TT + 1) * HH * BB;
  const size_t need   = (xt_f + 2 * ring_f) * 4 + 4096;
  const bool deep = (ws_size >= need);
  const size_t rslots = deep ? (size_t)(TT + 1) : 2;

  float* ws       = (float*)d_ws;
  float* xT       = ws;
  float* h0ring   = xT + xt_f;
  float* h1ring   = h0ring + rslots * HH * BB;
  unsigned* flags = (unsigned*)(h1ring + rslots * HH * BB);  // 256 u32

  k_transpose_x<<<1024, 1024, 0, stream>>>(x, xT);
  k_init_flags<<<1, NBLK, 0, stream>>>(flags);

  void* fn = deep ? (void*)k_lstm_persist<true> : (void*)k_lstm_persist<false>;
  hipFuncSetAttribute(fn, hipFuncAttributeMaxDynamicSharedMemorySize, SMEM_BYTES);

  void* args[] = {
    (void*)&xT,
    (void*)&W_ih0, (void*)&W_hh0, (void*)&b_ih0, (void*)&b_hh0,
    (void*)&W_ih1, (void*)&W_hh1, (void*)&b_ih1, (void*)&b_hh1,
    (void*)&h0ring, (void*)&h1ring, (void*)&flags,
  };
  // Cooperative launch kept ONLY for the co-residency guarantee; sync is ours.
  hipLaunchCooperativeKernel(fn, dim3(NBLK), dim3(1024), args, SMEM_BYTES, stream);

  // h1[T-1]: deep -> slot TT-1; fallback -> parity (TT-1)&1 == 1
  float* h1last = h1ring + (deep ? (size_t)(TT - 1) : (size_t)1) * HH * BB;
  k_final<<<1, 512, 0, stream>>>(h1last, Wl, bl, out);
}

// Round 17
// 7434.381 us; speedup vs baseline: 1.3326x; 1.0573x over previous
//
#include <hip/hip_runtime.h>
#include <cmath>

#define TT 512
#define BB 64
#define HH 512
#define II 128
#define NBLK 256

typedef float v2f __attribute__((ext_vector_type(2)));
__device__ __forceinline__ v2f fma2(v2f a, v2f b, v2f c) { return __builtin_elementwise_fma(a, b, c); }

// dynamic LDS floats: wlds 16*1024 =16384 | part 16*16*32*2 =16384 |
// gates 16*64 =1024 | cst 256 | bsum 16   => ~133 KB  (=> 1 block/CU)
#define SMEM_FLOATS (16384 + 16384 + 1024 + 256 + 16)
#define SMEM_BYTES  (SMEM_FLOATS * 4)

__device__ __forceinline__ float sigm(float v) { return 1.0f / (1.0f + expf(-v)); }
__device__ __forceinline__ unsigned umin2(unsigned a, unsigned b) { return a < b ? a : b; }
#define CBAR() asm volatile("" ::: "memory")   // compiler-only reorder fence

// 8-byte bypass (relaxed AGENT atomic) load of a batch-pair of h.
// Served from the coherence point — immune to stale local lines (r13-proven).
__device__ __forceinline__ v2f loadh2(const float* p) {
  unsigned long long r = __hip_atomic_load((const unsigned long long*)p,
                                           __ATOMIC_RELAXED, __HIP_MEMORY_SCOPE_AGENT);
  v2f v;
  v.x = __uint_as_float((unsigned)r);
  v.y = __uint_as_float((unsigned)(r >> 32));
  return v;
}
template<int KN>
__device__ __forceinline__ void loadh2b(const float* __restrict__ src, int k0,
                                        int bp, v2f (&v)[KN]) {
#pragma unroll
  for (int i = 0; i < KN; ++i) v[i] = loadh2(src + (size_t)(k0 + i) * BB + 2 * bp);
}
// x: plain cached 8B loads (immutable input, L2-resident).
template<int KN>
__device__ __forceinline__ void loadx2(const float* __restrict__ src, int k0,
                                       int bp, v2f (&v)[KN]) {
#pragma unroll
  for (int i = 0; i < KN; ++i)
    v[i] = *(const v2f*)(src + (size_t)(k0 + i) * BB + 2 * bp);
}

// One k for THIS lane's row-half (8 rows): 2 ds_read_b128 (2-address across
// the wave -> free 2-way) + 8 v_pk_fma over the lane's batch-pair.
__device__ __forceinline__ void step2(const float* wk8, v2f h2, v2f (&acc)[8]) {
  const float4* wp = (const float4*)wk8;
  const float4 w0 = wp[0], w1 = wp[1];
  acc[0] = fma2((v2f){w0.x, w0.x}, h2, acc[0]);
  acc[1] = fma2((v2f){w0.y, w0.y}, h2, acc[1]);
  acc[2] = fma2((v2f){w0.z, w0.z}, h2, acc[2]);
  acc[3] = fma2((v2f){w0.w, w0.w}, h2, acc[3]);
  acc[4] = fma2((v2f){w1.x, w1.x}, h2, acc[4]);
  acc[5] = fma2((v2f){w1.y, w1.y}, h2, acc[5]);
  acc[6] = fma2((v2f){w1.z, w1.z}, h2, acc[6]);
  acc[7] = fma2((v2f){w1.w, w1.w}, h2, acc[7]);
}
// wro = wlds_segment + rhalf*8 ; weight row-chunk for k at wro + k*16.
template<int KN>
__device__ __forceinline__ void consume2(const float* __restrict__ wro, int k0,
                                         const v2f (&v)[KN], v2f (&acc)[8]) {
#pragma unroll
  for (int i = 0; i < KN; ++i) step2(wro + (size_t)(k0 + i) * 16, v[i], acc);
}

// 32-k span, 4-deep ping-pong (8 v2f staging = 16 VGPRs -> no spills).
__device__ __forceinline__ void span32(const float* __restrict__ src,
                                       const float* __restrict__ wro,
                                       int k0, int bp, v2f (&acc)[8]) {
  v2f a[4], b[4];
  loadh2b<4>(src, k0,      bp, a);
  loadh2b<4>(src, k0 + 4,  bp, b);
  consume2<4>(wro, k0,      a, acc);
  loadh2b<4>(src, k0 + 8,  bp, a);
  consume2<4>(wro, k0 + 4,  b, acc);
  loadh2b<4>(src, k0 + 12, bp, b);
  consume2<4>(wro, k0 + 8,  a, acc);
  loadh2b<4>(src, k0 + 16, bp, a);
  consume2<4>(wro, k0 + 12, b, acc);
  loadh2b<4>(src, k0 + 20, bp, b);
  consume2<4>(wro, k0 + 16, a, acc);
  loadh2b<4>(src, k0 + 24, bp, a);
  consume2<4>(wro, k0 + 20, b, acc);
  loadh2b<4>(src, k0 + 28, bp, b);
  consume2<4>(wro, k0 + 24, a, acc);
  consume2<4>(wro, k0 + 28, b, acc);
}

// ---------------------------------------------------------------------------
// Transpose x: [64][512][128] (b,t,k) -> xT: [512][128][64] (t,k,b)
// ---------------------------------------------------------------------------
__global__ __launch_bounds__(1024) void k_transpose_x(const float* __restrict__ x,
                                                      float* __restrict__ xT) {
  __shared__ float tile[64][65];
  const int t  = blockIdx.x >> 1;
  const int k0 = (blockIdx.x & 1) << 6;
  const int lk = threadIdx.x & 63;
  const int lb = threadIdx.x >> 6;
#pragma unroll
  for (int bp = 0; bp < 64; bp += 16) {
    const int b = bp + lb;
    tile[lk][b] = x[((size_t)b * TT + t) * II + k0 + lk];
  }
  __syncthreads();
  const int b2  = threadIdx.x & 63;
  const int kk0 = threadIdx.x >> 6;
#pragma unroll
  for (int kp = 0; kp < 64; kp += 16) {
    const int kk = kp + kk0;
    xT[((size_t)t * II + k0 + kk) * BB + b2] = tile[kk][b2];
  }
}

__global__ void k_init_flags(unsigned* flags) { flags[threadIdx.x] = 0u; }

// ---------------------------------------------------------------------------
// Persistent pipelined 2-layer LSTM — round-13's proven zero-fence protocol
// (swap-with-return publish; bypass atomic consumer loads; full flag barrier;
// depth-2 parity rings). DELTA vs round 13 (the 7.52ms best): the LDS weight
// read is DE-UNIFORMED. Lane map: bp = lane&31 (batch-PAIR, v2f), rhalf =
// lane>>5 (rows 0-7 vs 8-15), kseg = tid>>6. Each lane reads only its row-
// half's 8 weights per k -> 2 ds_read_b128/k (2-address, free) instead of 4
// uniform ones, and one 8B h load per k instead of a 4B one. Per-phase LDS
// issue on the single LDS pipe halves: 4096 -> 2048 b128 (r14's chain fit
// showed ~7cy/b128 broadcast => ~12.5us/phase WAS the wall).
// ---------------------------------------------------------------------------
__global__ __launch_bounds__(1024, 4) void k_lstm_persist(
    const float* __restrict__ xT,
    const float* __restrict__ W_ih0, const float* __restrict__ W_hh0,
    const float* __restrict__ b_ih0, const float* __restrict__ b_hh0,
    const float* __restrict__ W_ih1, const float* __restrict__ W_hh1,
    const float* __restrict__ b_ih1, const float* __restrict__ b_hh1,
    float* __restrict__ h0ring, float* __restrict__ h1ring,
    unsigned* __restrict__ flags)
{
  extern __shared__ float smem[];
  float* wlds  = smem;            // [k up to 1024][16 rows] k-major
  float* part  = wlds + 16384;    // [row16][kseg16][bp32][2]
  float* gates = part + 16384;    // [row16][b64]
  float* cst   = gates + 1024;    // [u4][b64]
  float* bsum  = cst + 256;       // [16]

  const int bid = blockIdx.x;
  const int L   = bid >> 7;
  const int ub  = (bid & 127) << 2;   // 4 hidden units per block
  const int tid = threadIdx.x;

  const float* WA = L ? W_ih1 : W_ih0;
  const float* WB = L ? W_hh1 : W_hh0;
  const int KA = L ? HH : II;

  // ---- one-time: stage weights k-major + bias sums + c=0 ----
  const int ktot = KA + HH;
  for (int idx = tid; idx < 16 * ktot; idx += 1024) {
    const int k  = idx >> 4;
    const int lr = idx & 15;
    const int u = lr >> 2, q = lr & 3;
    const int G = q * HH + ub + u;           // i,f,g,o chunk order
    wlds[idx] = (k < KA) ? WA[G * KA + k] : WB[G * HH + (k - KA)];
  }
  if (tid < 16) {
    const int u = tid >> 2, q = tid & 3;
    const int G = q * HH + ub + u;
    bsum[tid] = L ? (b_ih1[G] + b_hh1[G]) : (b_ih0[G] + b_hh0[G]);
  }
  if (tid < 256) cst[tid] = 0.0f;
  __syncthreads();

  const int bp    = tid & 31;         // batch-pair index (b = 2bp, 2bp+1)
  const int rhalf = (tid >> 5) & 1;   // row half (0..7 / 8..15)
  const int kseg  = tid >> 6;         // 0..15

  const float* wroA = wlds + rhalf * 8;                     // A-operand rows
  const float* wroB0 = wlds + (size_t)II * 16 + rhalf * 8;  // L0 B rows
  const float* wroB1 = wlds + (size_t)HH * 16 + rhalf * 8;  // L1 B rows

  for (int s = 0; s <= TT; ++s) {
    const int t = L ? (s - 1) : s;
    const bool active = (t >= 0 && t < TT);
    const bool first  = (t == 0);

    v2f acc[8];
#pragma unroll
    for (int j = 0; j < 8; ++j) acc[j] = (v2f){0.0f, 0.0f};

    // ---- L0 x loads BEFORE the wait (immutable; complete during spin) ----
    v2f xa[4], xb[4];
    if (active && L == 0) {
      const float* xp = xT + (size_t)t * (II * BB);
      loadx2<4>(xp, kseg * 8,     bp, xa);
      loadx2<4>(xp, kseg * 8 + 4, bp, xb);
    }

    // ---- wait: all blocks published phase s-1 (no fence needed) ----
    if (s > 0) {
      if (tid < 64) {
        const unsigned tgt = (unsigned)s;
        for (;;) {
          const unsigned m0 = __hip_atomic_load(flags + tid,       __ATOMIC_RELAXED, __HIP_MEMORY_SCOPE_AGENT);
          const unsigned m1 = __hip_atomic_load(flags + tid +  64, __ATOMIC_RELAXED, __HIP_MEMORY_SCOPE_AGENT);
          const unsigned m2 = __hip_atomic_load(flags + tid + 128, __ATOMIC_RELAXED, __HIP_MEMORY_SCOPE_AGENT);
          const unsigned m3 = __hip_atomic_load(flags + tid + 192, __ATOMIC_RELAXED, __HIP_MEMORY_SCOPE_AGENT);
          const unsigned mn = umin2(umin2(m0, m1), umin2(m2, m3));
          if (__all(mn >= tgt)) break;
          __builtin_amdgcn_s_sleep(1);
        }
      }
      __syncthreads();
      CBAR();   // keep h loads below the spin at IR level
    }

    if (active) {
      if (L == 0) {
        consume2<4>(wroA, kseg * 8,     xa, acc);
        consume2<4>(wroA, kseg * 8 + 4, xb, acc);
        if (!first) {  // B-part: h0[s-1] @ parity (s-1)&1
          span32(h0ring + (size_t)((s - 1) & 1) * (HH * BB),
                 wroB0, kseg * 32, bp, acc);
        }
      } else {
        span32(h0ring + (size_t)((s - 1) & 1) * (HH * BB),
               wroA, kseg * 32, bp, acc);
        if (!first) {  // B-part: h1[s-2] @ parity s&1
          span32(h1ring + (size_t)(s & 1) * (HH * BB),
                 wroB1, kseg * 32, bp, acc);
        }
      }

      // ---- reduce 16 ksegs -> gates; part[row][kseg][bp] as v2f ----
#pragma unroll
      for (int j = 0; j < 8; ++j) {
        const int row = rhalf * 8 + j;
        *(v2f*)(part + ((((size_t)row * 16 + kseg) * 32 + bp) << 1)) = acc[j];
      }
      __syncthreads();
      {
        const int row = tid >> 6;
        const int bb  = tid & 63;
        float g = 0.0f;
#pragma unroll
        for (int ks = 0; ks < 16; ++ks)
          g += part[((((size_t)row * 16 + ks) * 32 + (bb >> 1)) << 1) + (bb & 1)];
        gates[row * 64 + bb] = g + bsum[row];
      }
      __syncthreads();

      if (tid < 256) {  // cell update; h published via swap-with-return
        const int u = tid >> 6, bb = tid & 63;
        const float gi = sigm(gates[((u << 2) + 0) * 64 + bb]);
        const float gf = sigm(gates[((u << 2) + 1) * 64 + bb]);
        const float gg = tanhf(gates[((u << 2) + 2) * 64 + bb]);
        const float go = sigm(gates[((u << 2) + 3) * 64 + bb]);
        const float cold = first ? 0.0f : cst[u * 64 + bb];
        const float cn = gf * cold + gi * gg;
        const float hn = go * tanhf(cn);
        cst[u * 64 + bb] = cn;
        float* hdst = (L ? h1ring : h0ring) + (size_t)(t & 1) * (HH * BB);
        // swap-with-return: performed AT the MALL; asm sink forces the
        // s_waitcnt on the return before the barrier below (r13-proven).
        float old = __hip_atomic_exchange(hdst + (ub + u) * 64 + bb, hn,
                                          __ATOMIC_RELAXED, __HIP_MEMORY_SCOPE_AGENT);
        asm volatile("" :: "v"(old));
      }
    }

    // all swaps' returns received (h at MALL) before any thread passes here;
    // the flag store is issued strictly afterwards -> cannot be seen early.
    __syncthreads();
    if (tid == 0) {
      __hip_atomic_store(flags + bid, (unsigned)(s + 1),
                         __ATOMIC_RELAXED, __HIP_MEMORY_SCOPE_AGENT);
    }
  }
}

// ---------------------------------------------------------------------------
// out[b] = sum_j h1_last[j][b] * Wl[j] + bl[0]
// ---------------------------------------------------------------------------
__global__ __launch_bounds__(512) void k_final(const float* __restrict__ h1last,
                                               const float* __restrict__ Wl,
                                               const float* __restrict__ bl,
                                               float* __restrict__ out) {
  __shared__ float red[8][64];
  const int jg = threadIdx.x >> 6, b = threadIdx.x & 63;
  float a = 0.0f;
  for (int jj = 0; jj < 64; ++jj) {
    const int j = (jg << 6) + jj;
    a += h1last[j * BB + b] * Wl[j];
  }
  red[jg][b] = a;
  __syncthreads();
  if (threadIdx.x < 64) {
    float s = bl[0];
#pragma unroll
    for (int g = 0; g < 8; ++g) s += red[g][threadIdx.x];
    out[threadIdx.x] = s;
  }
}

extern "C" void kernel_launch(void* const* d_in, const int* in_sizes, int n_in,
                              void* d_out, int out_size, void* d_ws, size_t ws_size,
                              hipStream_t stream) {
  (void)in_sizes; (void)n_in; (void)out_size; (void)ws_size;
  const float* x     = (const float*)d_in[0];
  const float* W_ih0 = (const float*)d_in[1];
  const float* W_hh0 = (const float*)d_in[2];
  const float* b_ih0 = (const float*)d_in[3];
  const float* b_hh0 = (const float*)d_in[4];
  const float* W_ih1 = (const float*)d_in[5];
  const float* W_hh1 = (const float*)d_in[6];
  const float* b_ih1 = (const float*)d_in[7];
  const float* b_hh1 = (const float*)d_in[8];
  const float* Wl    = (const float*)d_in[9];
  const float* bl    = (const float*)d_in[10];
  float* out = (float*)d_out;

  float* ws       = (float*)d_ws;
  float* xT       = ws;                         // 512*128*64
  float* h0ring   = xT + (size_t)TT * II * BB;  // 2*512*64
  float* h1ring   = h0ring + 2 * HH * BB;       // 2*512*64
  unsigned* flags = (unsigned*)(h1ring + 2 * HH * BB);  // 256 u32

  k_transpose_x<<<1024, 1024, 0, stream>>>(x, xT);
  k_init_flags<<<1, NBLK, 0, stream>>>(flags);

  hipFuncSetAttribute((const void*)k_lstm_persist,
                      hipFuncAttributeMaxDynamicSharedMemorySize, SMEM_BYTES);

  void* args[] = {
    (void*)&xT,
    (void*)&W_ih0, (void*)&W_hh0, (void*)&b_ih0, (void*)&b_hh0,
    (void*)&W_ih1, (void*)&W_hh1, (void*)&b_ih1, (void*)&b_hh1,
    (void*)&h0ring, (void*)&h1ring, (void*)&flags,
  };
  // Cooperative launch kept ONLY for the co-residency guarantee; sync is ours.
  hipLaunchCooperativeKernel((void*)k_lstm_persist, dim3(NBLK), dim3(1024),
                             args, SMEM_BYTES, stream);

  // h1[T-1] lives at ring parity (T-1)&1 == 1
  k_final<<<1, 512, 0, stream>>>(h1ring + HH * BB, Wl, bl, out);
}